// Round 15
// baseline (192.666 us; speedup 1.0000x reference)
//
#include <hip/hip_runtime.h>
#include <cstdint>
#include <cstddef>

#define NBm 256
#define NAm 96
#define NDm 384
#define NHm 192
#define NFm 96
#define NSm 4
#define NATOMS (NBm*NAm)      /* 24576 */
#define NEe (NATOMS*32)       /* 786432 */
#define CUTOFF_ 5.2f
#define PBLK 256              /* edge-accum blocks = partial copies */
#define EPB (NEe/PBLK)        /* 3072 edges per block */
#define HBLK 96               /* NATOMS/256 hist blocks */

typedef __attribute__((ext_vector_type(8))) short short8;
typedef __attribute__((ext_vector_type(4))) float float4v;

__device__ __forceinline__ short f2bf(float f){
  union { float f; unsigned u; } v; v.f = f;
  unsigned r = v.u + 0x7FFFu + ((v.u >> 16) & 1u);
  return (short)(r >> 16);
}

// jax.nn.gelu default: tanh approximation
__device__ __forceinline__ float gelu_t(float x){
  float u = 0.7978845608028654f * (x + 0.044715f * x*x*x);
  float e = __expf(-2.0f * fabsf(u));
  float t = (1.0f - e) / (1.0f + e);
  t = (u >= 0.f) ? t : -t;
  return 0.5f * x * (1.0f + t);
}

// ---------- K1: weight prep + per-block species histogram (R14-verified) ----------
#define W1N (NSm*NDm*NHm)   /* 294912 */
#define W2N (NSm*NHm*NFm)   /* 73728 */
#define WNN (NSm*NFm*NFm)   /* 36864 */
#define WTOT (W1N+W2N+WNN)  /* 405504 */
#define WBLK (WTOT/256)     /* 1584 */
// grid = WBLK + HBLK = 1680
__global__ __launch_bounds__(256) void k_prep(
    const float* __restrict__ W1, const float* __restrict__ W2,
    const float* __restrict__ Wn, const int* __restrict__ sp,
    short* __restrict__ W1t, short* __restrict__ W2t, short* __restrict__ Wnt,
    int* __restrict__ Pcnt){
  int b = blockIdx.x;
  if (b < WBLK){
    int idx = b*256 + threadIdx.x;
    if (idx < W1N){
      int s = idx / (NDm*NHm); int rem = idx - s*NDm*NHm;
      int k = rem / NHm, c = rem - k*NHm;
      W1t[(s*NHm + c)*NDm + k] = f2bf(W1[idx]);
    } else if (idx < W1N + W2N){
      int j = idx - W1N;
      int s = j / (NHm*NFm); int rem = j - s*NHm*NFm;
      int k = rem / NFm, c = rem - k*NFm;
      W2t[(s*NFm + c)*NHm + k] = f2bf(W2[j]);
    } else {
      int j = idx - W1N - W2N;
      int s = j / (NFm*NFm); int rem = j - s*NFm*NFm;
      int k = rem / NFm, c = rem - k*NFm;
      Wnt[(s*NFm + c)*NFm + k] = f2bf(Wn[j]);
    }
  } else {
    // per-block species histogram; LDS atomics only, no pre-zero needed
    __shared__ int h[NSm];
    int t = threadIdx.x;
    if (t < NSm) h[t] = 0;
    __syncthreads();
    int i = (b - WBLK)*256 + t;
    atomicAdd(&h[sp[i]], 1);
    __syncthreads();
    if (t < NSm) Pcnt[(b - WBLK)*NSm + t] = h[t];
  }
}

// ---------- K2: redundant-scan ordering (R14-verified) ----------
__global__ __launch_bounds__(256) void k_order(const int* __restrict__ sp,
    const int* __restrict__ Pcnt, int* __restrict__ sps, int* __restrict__ order){
  __shared__ int P[HBLK][NSm];
  __shared__ int stot[NSm], spre[NSm], sscan[NSm+1];
  __shared__ int base[NSm], h[NSm];
  int t = threadIdx.x, b = blockIdx.x;
  if (t < HBLK){
    #pragma unroll
    for (int j=0;j<NSm;j++) P[t][j] = Pcnt[t*NSm + j];
  }
  if (t < NSm) h[t] = 0;
  __syncthreads();
  if (t < NSm){
    int tot = 0, pr = 0;
    for (int bb=0; bb<HBLK; bb++){
      if (bb == b) pr = tot;
      tot += P[bb][t];
    }
    stot[t] = tot; spre[t] = pr;
  }
  __syncthreads();
  if (t == 0){
    int r = 0;
    #pragma unroll
    for (int s2=0;s2<NSm;s2++){ sscan[s2] = r; r += stot[s2]; }
    sscan[NSm] = r;
    if (b == 0){
      #pragma unroll
      for (int s2=0;s2<=NSm;s2++) sps[s2] = sscan[s2];
    }
  }
  __syncthreads();
  if (t < NSm) base[t] = sscan[t] + spre[t];
  __syncthreads();
  int i = b*256 + t;
  int s = sp[i];
  int lr = atomicAdd(&h[s], 1);
  order[base[s] + lr] = i;
}

// ---------- fused MLP: DE-STAGED weights (direct L2 fragment reads) ----------
// R14 counters: 41.8us, MfmaUtil 4%, Occ 13.7%, 1.52M LDS conflicts, 79.4KB LDS.
// Weights (808KB total) are L2-resident; LDS staging bought barrier serialization.
// This version reads B fragments straight from W1t/W2t/Wnt with the IDENTICAL
// index algebra (bfb values bit-identical, MFMA order unchanged), deletes Ws
// (39.9KB) and all GEMM barriers. NL aliases dead Hs. LDS 39.2KB -> 4 blk/CU.
__global__ __launch_bounds__(256) void k_mlp(
    const float* __restrict__ X, const int* __restrict__ order,
    const int* __restrict__ sps,
    const short* __restrict__ W1t, const short* __restrict__ W2t,
    const short* __restrict__ Wnt, const float* __restrict__ Wf,
    float* __restrict__ pre, float* __restrict__ nd4){
  const int s = blockIdx.y;
  const int s0 = sps[s];
  const int cnt = sps[s+1] - s0;
  const int row0 = blockIdx.x * 64;
  if (row0 >= cnt) return;

  __shared__ short Hs[64][200];     // 25.6 KB (aliased as NL in epilogue B)
  __shared__ short Is[64][104];     // 13.3 KB
  __shared__ int aids[64];

  const int tid = threadIdx.x;
  if (tid < 64){
    int r = row0 + tid;
    aids[tid] = order[s0 + ((r < cnt) ? r : 0)];
  }
  __syncthreads();

  const int wave = tid >> 6, lane = tid & 63;
  const int lrow = lane & 15, quad = lane >> 4;
  const int arow = wave*16 + lrow;
  const float* xrow = X + (size_t)aids[arow]*NDm + quad*8;

  // preload & convert all A fragments (GEMM1) up front
  short8 afs[12];
  #pragma unroll
  for (int kb=0; kb<12; kb++){
    const float* p = xrow + kb*32;
    #pragma unroll
    for (int j=0;j<8;j++) afs[kb][j] = f2bf(p[j]);
  }

  // ---- GEMM1: [64,384]@[384,192]; B fragments direct from L2 (no barriers)
  const short* W1s = W1t + (size_t)s*NHm*NDm;
  float4v acc[12];
  #pragma unroll
  for (int i=0;i<12;i++){ acc[i][0]=0.f; acc[i][1]=0.f; acc[i][2]=0.f; acc[i][3]=0.f; }
  for (int kb=0; kb<12; kb++){
    short8 af = afs[kb];
    #pragma unroll
    for (int ct=0; ct<12; ct++){
      short8 bfb = *(const short8*)(W1s + (size_t)(ct*16 + lrow)*NDm + kb*32 + quad*8);
      acc[ct] = __builtin_amdgcn_mfma_f32_16x16x32_bf16(af, bfb, acc[ct], 0,0,0);
    }
  }
  // gelu -> Hs (wave-private rows, no barrier)
  #pragma unroll
  for (int ct=0; ct<12; ct++){
    #pragma unroll
    for (int r=0;r<4;r++){
      Hs[wave*16 + quad*4 + r][ct*16 + lrow] = f2bf(gelu_t(acc[ct][r]));
    }
  }

  // ---- GEMM2: [64,192]@[192,96]; B direct from L2
  const short* W2s = W2t + (size_t)s*NFm*NHm;
  float4v acc2[6];
  #pragma unroll
  for (int i=0;i<6;i++){ acc2[i][0]=0.f; acc2[i][1]=0.f; acc2[i][2]=0.f; acc2[i][3]=0.f; }
  for (int kb=0; kb<6; kb++){
    short8 af2 = *(const short8*)(&Hs[wave*16 + lrow][kb*32 + quad*8]);
    #pragma unroll
    for (int ct=0; ct<6; ct++){
      short8 bfb = *(const short8*)(W2s + (size_t)(ct*16 + lrow)*NHm + kb*32 + quad*8);
      acc2[ct] = __builtin_amdgcn_mfma_f32_16x16x32_bf16(af2, bfb, acc2[ct], 0,0,0);
    }
  }
  // internal -> Is (wave-private)
  #pragma unroll
  for (int ct=0; ct<6; ct++){
    #pragma unroll
    for (int r=0;r<4;r++){
      Is[wave*16 + quad*4 + r][ct*16 + lrow] = f2bf(acc2[ct][r]);
    }
  }

  // ---- epilogue A (verified): pre = dot(internal_row, Wf[s][0:96])
  {
    float pr[4] = {0.f,0.f,0.f,0.f};
    #pragma unroll
    for (int ct=0; ct<6; ct++){
      float wv = Wf[s*2*NFm + ct*16 + lrow];
      #pragma unroll
      for (int r=0;r<4;r++) pr[r] += acc2[ct][r] * wv;
    }
    #pragma unroll
    for (int m=1; m<16; m<<=1){
      #pragma unroll
      for (int r=0;r<4;r++) pr[r] += __shfl_xor(pr[r], m, 64);
    }
    if (lrow == 0){
      #pragma unroll
      for (int r=0;r<4;r++){
        int row = wave*16 + quad*4 + r;
        if (row0 + row < cnt) pre[aids[row]] = pr[r];
      }
    }
  }

  // ---- GEMM3: [64,96]@[96,96]; B direct from L2
  const short* Wns = Wnt + (size_t)s*NFm*NFm;
  float4v acc3[6];
  #pragma unroll
  for (int i=0;i<6;i++){ acc3[i][0]=0.f; acc3[i][1]=0.f; acc3[i][2]=0.f; acc3[i][3]=0.f; }
  for (int kb=0; kb<3; kb++){
    short8 af3 = *(const short8*)(&Is[wave*16 + lrow][kb*32 + quad*8]);
    #pragma unroll
    for (int ct=0; ct<6; ct++){
      short8 bfb = *(const short8*)(Wns + (size_t)(ct*16 + lrow)*NFm + kb*32 + quad*8);
      acc3[ct] = __builtin_amdgcn_mfma_f32_16x16x32_bf16(af3, bfb, acc3[ct], 0,0,0);
    }
  }

  // ---- epilogue B (LDS-staged via NL=Hs alias, R12-verified mapping)
  {
    float* NL = (float*)Hs;            // Hs dead after all waves pass barrier
    __syncthreads();                   // all waves done reading Hs (GEMM2) & Is (GEMM3)
    #pragma unroll
    for (int ct=0; ct<6; ct++){
      #pragma unroll
      for (int r=0;r<4;r++){
        NL[(wave*16 + quad*4 + r)*97 + ct*16 + lrow] = acc3[ct][r];
      }
    }
    __syncthreads();
    int row = tid >> 2, t2 = tid & 3;
    if (row0 + row < cnt){
      const float* wfp = Wf + t2*2*NFm + NFm;
      const float* nlr = NL + row*97;
      float a4 = 0.f;
      #pragma unroll 8
      for (int j=0;j<NFm;j++) a4 += nlr[j] * wfp[j];
      nd4[(size_t)aids[row]*4 + t2] = a4;
    }
  }
}

// ---------- K-eacc: edge accumulate via full-mrg LDS privatization (R8-verified) ----------
__global__ __launch_bounds__(1024) void k_eacc(const int* __restrict__ ai,
    const float* __restrict__ dist, const float* __restrict__ pref,
    const float* __restrict__ fac, const int* __restrict__ sp,
    const float* __restrict__ nd4, float* __restrict__ part){
  __shared__ float acc[NATOMS];    // 96 KB
  const int t = threadIdx.x, b = blockIdx.x;
  #pragma unroll
  for (int k=0;k<NATOMS/1024;k++) acc[k*1024 + t] = 0.f;   // 24 stores
  __syncthreads();
  const float p = pref[0], fc = fac[0];
  const int base = b*EPB;
  #pragma unroll
  for (int k=0;k<EPB/1024;k++){    // 3 edges/thread, coalesced
    int e = base + k*1024 + t;
    int i0 = ai[e];
    int i1 = ai[NEe + e];
    float d = dist[e];
    int s0 = sp[i0], s1 = sp[i1];
    float4v n1v = *(const float4v*)(nd4 + (size_t)i1*4);
    float4v n0v = *(const float4v*)(nd4 + (size_t)i0*4);
    float x = (CUTOFF_ - d) * (1.0f/CUTOFF_);
    x = fminf(fmaxf(x, 0.f), 1.f);
    float sc = x*x*x*(x*(6.f*x - 15.f) + 10.f);
    float w = p*p * expf(-fc*fc*d) * sc;
    float a1 = (s0 < 2) ? ((s0 == 0) ? n1v[0] : n1v[1]) : ((s0 == 2) ? n1v[2] : n1v[3]);
    float a0 = (s1 < 2) ? ((s1 == 0) ? n0v[0] : n0v[1]) : ((s1 == 2) ? n0v[2] : n0v[3]);
    atomicAdd(&acc[i0], w * a1);
    atomicAdd(&acc[i1], w * a0);
  }
  __syncthreads();
  float* dst = part + (size_t)b*NATOMS;
  for (int k=t; k<NATOMS/4; k+=1024){            // 6 x float4 stores, coalesced
    *(float4v*)(dst + k*4) = *(const float4v*)(&acc[k*4]);
  }
}

// ---------- per-molecule: 256-partial reduce + charge redistribution (R8-verified) ----------
__global__ __launch_bounds__(128) void k_final(const float* __restrict__ pre,
    const float* __restrict__ part, const int* __restrict__ sp,
    const float* __restrict__ tc, float* __restrict__ out){
  __shared__ float red[128];
  int mol = blockIdx.x, t = threadIdx.x;
  float pch = 0.f; int s = 0;
  if (t < NAm){
    int a = mol*NAm + t;
    s = sp[a];
    float m = 0.f;
    #pragma unroll 8
    for (int b=0; b<PBLK; b++) m += part[(size_t)b*NATOMS + a];
    pch = pre[a] + m;
  }
  red[t] = (t < NAm) ? pch : 0.f;
  __syncthreads();
  for (int o=64; o>0; o>>=1){
    if (t < o) red[t] += red[t + o];
    __syncthreads();
  }
  float sum = red[0];
  if (t < NAm){
    out[mol*NAm + t] = (float)s;                       // species as float
    out[NATOMS + mol*NAm + t] = pch + (tc[mol] - sum) * (1.0f/96.0f);  // charges
    out[2*NATOMS + mol*NAm + t] = pch;                 // precharges
  }
}

extern "C" void kernel_launch(void* const* d_in, const int* in_sizes, int n_in,
                              void* d_out, int out_size, void* d_ws, size_t ws_size,
                              hipStream_t stream) {
  const int*   species = (const int*)  d_in[0];
  const float* X       = (const float*)d_in[1];
  const int*   ai      = (const int*)  d_in[2];
  const float* dist    = (const float*)d_in[3];
  const float* tc      = (const float*)d_in[4];
  const float* W1      = (const float*)d_in[5];
  const float* W2      = (const float*)d_in[6];
  const float* Wn      = (const float*)d_in[7];
  const float* Wf      = (const float*)d_in[8];
  const float* pref    = (const float*)d_in[9];
  const float* fac     = (const float*)d_in[10];
  float* out = (float*)d_out;

  char* w = (char*)d_ws;
  auto alloc = [&](size_t bytes)->char*{
    char* p = w; w += (bytes + 255) & ~(size_t)255; return p;
  };
  int*   Pcnt  = (int*)  alloc((size_t)HBLK*NSm*4);
  int*   sps   = (int*)  alloc(64);
  int*   order = (int*)  alloc((size_t)NATOMS*4);
  float* nd4   = (float*)alloc((size_t)NATOMS*4*4);
  float* pre   = (float*)alloc((size_t)NATOMS*4);
  float* part  = (float*)alloc((size_t)PBLK*NATOMS*4);   // 25.2 MB
  short* W1t   = (short*)alloc((size_t)W1N*2);
  short* W2t   = (short*)alloc((size_t)W2N*2);
  short* Wnt   = (short*)alloc((size_t)WNN*2);

  k_prep<<<WBLK + HBLK, 256, 0, stream>>>(W1, W2, Wn, species, W1t, W2t, Wnt, Pcnt);
  k_order<<<HBLK, 256, 0, stream>>>(species, Pcnt, sps, order);
  dim3 g(NATOMS/64, NSm);
  k_mlp<<<g, 256, 0, stream>>>(X, order, sps, W1t, W2t, Wnt, Wf, pre, nd4);
  k_eacc<<<PBLK, 1024, 0, stream>>>(ai, dist, pref, fac, species, nd4, part);
  k_final<<<NBm, 128, 0, stream>>>(pre, part, species, tc, out);
}

// Round 17
// 185.372 us; speedup vs baseline: 1.0393x; 1.0393x over previous
//
#include <hip/hip_runtime.h>
#include <cstdint>
#include <cstddef>

#define NBm 256
#define NAm 96
#define NDm 384
#define NHm 192
#define NFm 96
#define NSm 4
#define NATOMS (NBm*NAm)      /* 24576 */
#define NEe (NATOMS*32)       /* 786432 */
#define CUTOFF_ 5.2f
#define PBLK 256              /* edge-accum blocks = partial copies */
#define EPB (NEe/PBLK)        /* 3072 edges per block */
#define HBLK 96               /* NATOMS/256 hist blocks */

typedef __attribute__((ext_vector_type(8))) short short8;
typedef __attribute__((ext_vector_type(4))) float float4v;

__device__ __forceinline__ short f2bf(float f){
  union { float f; unsigned u; } v; v.f = f;
  unsigned r = v.u + 0x7FFFu + ((v.u >> 16) & 1u);
  return (short)(r >> 16);
}

// jax.nn.gelu default: tanh approximation
__device__ __forceinline__ float gelu_t(float x){
  float u = 0.7978845608028654f * (x + 0.044715f * x*x*x);
  float e = __expf(-2.0f * fabsf(u));
  float t = (1.0f - e) / (1.0f + e);
  t = (u >= 0.f) ? t : -t;
  return 0.5f * x * (1.0f + t);
}

// ---------- K1: weight prep + per-block species histogram (R14-verified) ----------
#define W1N (NSm*NDm*NHm)   /* 294912 */
#define W2N (NSm*NHm*NFm)   /* 73728 */
#define WNN (NSm*NFm*NFm)   /* 36864 */
#define WTOT (W1N+W2N+WNN)  /* 405504 */
#define WBLK (WTOT/256)     /* 1584 */
// grid = WBLK + HBLK = 1680
__global__ __launch_bounds__(256) void k_prep(
    const float* __restrict__ W1, const float* __restrict__ W2,
    const float* __restrict__ Wn, const int* __restrict__ sp,
    short* __restrict__ W1t, short* __restrict__ W2t, short* __restrict__ Wnt,
    int* __restrict__ Pcnt){
  int b = blockIdx.x;
  if (b < WBLK){
    int idx = b*256 + threadIdx.x;
    if (idx < W1N){
      int s = idx / (NDm*NHm); int rem = idx - s*NDm*NHm;
      int k = rem / NHm, c = rem - k*NHm;
      W1t[(s*NHm + c)*NDm + k] = f2bf(W1[idx]);
    } else if (idx < W1N + W2N){
      int j = idx - W1N;
      int s = j / (NHm*NFm); int rem = j - s*NHm*NFm;
      int k = rem / NFm, c = rem - k*NFm;
      W2t[(s*NFm + c)*NHm + k] = f2bf(W2[j]);
    } else {
      int j = idx - W1N - W2N;
      int s = j / (NFm*NFm); int rem = j - s*NFm*NFm;
      int k = rem / NFm, c = rem - k*NFm;
      Wnt[(s*NFm + c)*NFm + k] = f2bf(Wn[j]);
    }
  } else {
    // per-block species histogram; LDS atomics only, no pre-zero needed
    __shared__ int h[NSm];
    int t = threadIdx.x;
    if (t < NSm) h[t] = 0;
    __syncthreads();
    int i = (b - WBLK)*256 + t;
    atomicAdd(&h[sp[i]], 1);
    __syncthreads();
    if (t < NSm) Pcnt[(b - WBLK)*NSm + t] = h[t];
  }
}

// ---------- K2: redundant-scan ordering (R14-verified) ----------
__global__ __launch_bounds__(256) void k_order(const int* __restrict__ sp,
    const int* __restrict__ Pcnt, int* __restrict__ sps, int* __restrict__ order){
  __shared__ int P[HBLK][NSm];
  __shared__ int stot[NSm], spre[NSm], sscan[NSm+1];
  __shared__ int base[NSm], h[NSm];
  int t = threadIdx.x, b = blockIdx.x;
  if (t < HBLK){
    #pragma unroll
    for (int j=0;j<NSm;j++) P[t][j] = Pcnt[t*NSm + j];
  }
  if (t < NSm) h[t] = 0;
  __syncthreads();
  if (t < NSm){
    int tot = 0, pr = 0;
    for (int bb=0; bb<HBLK; bb++){
      if (bb == b) pr = tot;
      tot += P[bb][t];
    }
    stot[t] = tot; spre[t] = pr;
  }
  __syncthreads();
  if (t == 0){
    int r = 0;
    #pragma unroll
    for (int s2=0;s2<NSm;s2++){ sscan[s2] = r; r += stot[s2]; }
    sscan[NSm] = r;
    if (b == 0){
      #pragma unroll
      for (int s2=0;s2<=NSm;s2++) sps[s2] = sscan[s2];
    }
  }
  __syncthreads();
  if (t < NSm) base[t] = sscan[t] + spre[t];
  __syncthreads();
  int i = b*256 + t;
  int s = sp[i];
  int lr = atomicAdd(&h[s], 1);
  order[base[s] + lr] = i;
}

// ---------- fused MLP: R14 staged structure, 8 waves via column-split ----------
// R15 lesson: occupancy was GRID-capped (1536 waves = 6/CU), not LDS-capped;
// de-staging regressed (L2 latency per MFMA). This keeps R14's verified staged
// dataflow and doubles waves: 512 threads, wave w -> rg=w>>1 (16 rows),
// cs=w&1 (column half). 3072 waves = 12/CU. Epilogue A uses the R12-verified
// LDS serial-dot mechanism (acc2 f32 staged to dead-Hs alias); no new shfl.
__global__ __launch_bounds__(512) void k_mlp(
    const float* __restrict__ X, const int* __restrict__ order,
    const int* __restrict__ sps,
    const short* __restrict__ W1t, const short* __restrict__ W2t,
    const short* __restrict__ Wnt, const float* __restrict__ Wf,
    float* __restrict__ pre, float* __restrict__ nd4){
  const int s = blockIdx.y;
  const int s0 = sps[s];
  const int cnt = sps[s+1] - s0;
  const int row0 = blockIdx.x * 64;
  if (row0 >= cnt) return;

  __shared__ short Hs[64][200];     // 25.6 KB (f32-aliased as NL, 64*97*4=24.8KB)
  __shared__ short Is[64][104];     // 13.3 KB
  __shared__ short Ws[19968];       // 39.9 KB staging buffer
  __shared__ int aids[64];

  const int tid = threadIdx.x;
  if (tid < 64){
    int r = row0 + tid;
    aids[tid] = order[s0 + ((r < cnt) ? r : 0)];
  }
  __syncthreads();

  const int wave = tid >> 6, lane = tid & 63;
  const int rg = wave >> 1;          // row group 0..3 (16 rows each)
  const int cs = wave & 1;           // column half
  const int lrow = lane & 15, quad = lane >> 4;
  const int arow = rg*16 + lrow;
  const float* xrow = X + (size_t)aids[arow]*NDm + quad*8;

  // preload & convert all A fragments (GEMM1) up front
  short8 afs[12];
  #pragma unroll
  for (int kb=0; kb<12; kb++){
    const float* p = xrow + kb*32;
    #pragma unroll
    for (int j=0;j<8;j++) afs[kb][j] = f2bf(p[j]);
  }

  // ---- GEMM1: [64,384]@[384,192]; 4 staged chunks of K=96; 6 ct per wave
  const short* W1s = W1t + (size_t)s*NHm*NDm;
  float4v acc[6];
  #pragma unroll
  for (int i=0;i<6;i++){ acc[i][0]=0.f; acc[i][1]=0.f; acc[i][2]=0.f; acc[i][3]=0.f; }
  for (int kc=0; kc<4; kc++){
    __syncthreads();
    for (int e = tid; e < 192*12; e += 512){   // 192 cols x 12 short8 units
      int c = e / 12, u = e - c*12;
      *(short8*)(&Ws[c*104 + u*8]) = *(const short8*)(W1s + c*NDm + kc*96 + u*8);
    }
    __syncthreads();
    #pragma unroll
    for (int kb3=0; kb3<3; kb3++){
      short8 af = afs[kc*3 + kb3];
      #pragma unroll
      for (int ct=0; ct<6; ct++){
        int ctt = cs*6 + ct;
        short8 bfb = *(const short8*)(&Ws[(ctt*16 + lrow)*104 + kb3*32 + quad*8]);
        acc[ct] = __builtin_amdgcn_mfma_f32_16x16x32_bf16(af, bfb, acc[ct], 0,0,0);
      }
    }
  }
  // gelu -> Hs (rows shared by wave pair, cols disjoint)
  #pragma unroll
  for (int ct=0; ct<6; ct++){
    int ctt = cs*6 + ct;
    #pragma unroll
    for (int r=0;r<4;r++){
      Hs[rg*16 + quad*4 + r][ctt*16 + lrow] = f2bf(gelu_t(acc[ct][r]));
    }
  }

  // ---- GEMM2: [64,192]@[192,96]; stage whole W2 once; 3 ct per wave
  const short* W2s = W2t + (size_t)s*NFm*NHm;
  float4v acc2[3];
  #pragma unroll
  for (int i=0;i<3;i++){ acc2[i][0]=0.f; acc2[i][1]=0.f; acc2[i][2]=0.f; acc2[i][3]=0.f; }
  __syncthreads();                   // Hs writes + last Ws reads complete
  for (int e = tid; e < 96*24; e += 512){      // 96 cols x 24 short8 units (K=192)
    int c = e / 24, u = e - c*24;
    *(short8*)(&Ws[c*200 + u*8]) = *(const short8*)(W2s + c*NHm + u*8);
  }
  __syncthreads();
  for (int kb=0; kb<6; kb++){
    short8 af2 = *(const short8*)(&Hs[rg*16 + lrow][kb*32 + quad*8]);
    #pragma unroll
    for (int ct=0; ct<3; ct++){
      int ctt = cs*3 + ct;
      short8 bfb = *(const short8*)(&Ws[(ctt*16 + lrow)*200 + kb*32 + quad*8]);
      acc2[ct] = __builtin_amdgcn_mfma_f32_16x16x32_bf16(af2, bfb, acc2[ct], 0,0,0);
    }
  }

  float* NL = (float*)Hs;            // f32 alias of Hs (dead after barrier below)
  __syncthreads();                   // all Hs reads (GEMM2) complete
  // internal -> Is (bf16, for GEMM3) and -> NL (f32, for epilogue A)
  #pragma unroll
  for (int ct=0; ct<3; ct++){
    int ctt = cs*3 + ct;
    #pragma unroll
    for (int r=0;r<4;r++){
      Is[rg*16 + quad*4 + r][ctt*16 + lrow] = f2bf(acc2[ct][r]);
      NL[(rg*16 + quad*4 + r)*97 + ctt*16 + lrow] = acc2[ct][r];
    }
  }
  // stage Wn into Ws (Ws reads done at barrier above)
  const short* Wns = Wnt + (size_t)s*NFm*NFm;
  for (int e = tid; e < 96*12; e += 512){      // 96 cols x 12 short8 units (K=96)
    int c = e / 12, u = e - c*12;
    *(short8*)(&Ws[c*104 + u*8]) = *(const short8*)(Wns + c*NFm + u*8);
  }
  __syncthreads();

  // ---- epilogue A (R12-verified serial-dot mechanism): pre = dot(internal, Wf[s][0:96])
  if (tid < 64){
    int row = tid;
    if (row0 + row < cnt){
      const float* wfp = Wf + s*2*NFm;
      const float* nlr = NL + row*97;
      float pr = 0.f;
      #pragma unroll 8
      for (int j=0;j<NFm;j++) pr += nlr[j] * wfp[j];
      pre[aids[row]] = pr;
    }
  }

  // ---- GEMM3: [64,96]@[96,96]; 3 ct per wave
  float4v acc3[3];
  #pragma unroll
  for (int i=0;i<3;i++){ acc3[i][0]=0.f; acc3[i][1]=0.f; acc3[i][2]=0.f; acc3[i][3]=0.f; }
  for (int kb=0; kb<3; kb++){
    short8 af3 = *(const short8*)(&Is[rg*16 + lrow][kb*32 + quad*8]);
    #pragma unroll
    for (int ct=0; ct<3; ct++){
      int ctt = cs*3 + ct;
      short8 bfb = *(const short8*)(&Ws[(ctt*16 + lrow)*104 + kb*32 + quad*8]);
      acc3[ct] = __builtin_amdgcn_mfma_f32_16x16x32_bf16(af3, bfb, acc3[ct], 0,0,0);
    }
  }

  // ---- epilogue B (R12-verified): nd4[a][t2] = dot(nbr_row, Wf[t2][F:2F])
  __syncthreads();                   // epilogue A's NL reads complete
  #pragma unroll
  for (int ct=0; ct<3; ct++){
    int ctt = cs*3 + ct;
    #pragma unroll
    for (int r=0;r<4;r++){
      NL[(rg*16 + quad*4 + r)*97 + ctt*16 + lrow] = acc3[ct][r];
    }
  }
  __syncthreads();
  if (tid < 256){
    int row = tid >> 2, t2 = tid & 3;
    if (row0 + row < cnt){
      const float* wfp = Wf + t2*2*NFm + NFm;
      const float* nlr = NL + row*97;
      float a4 = 0.f;
      #pragma unroll 8
      for (int j=0;j<NFm;j++) a4 += nlr[j] * wfp[j];
      nd4[(size_t)aids[row]*4 + t2] = a4;
    }
  }
}

// ---------- K-eacc: edge accumulate via full-mrg LDS privatization (R8-verified) ----------
__global__ __launch_bounds__(1024) void k_eacc(const int* __restrict__ ai,
    const float* __restrict__ dist, const float* __restrict__ pref,
    const float* __restrict__ fac, const int* __restrict__ sp,
    const float* __restrict__ nd4, float* __restrict__ part){
  __shared__ float acc[NATOMS];    // 96 KB
  const int t = threadIdx.x, b = blockIdx.x;
  #pragma unroll
  for (int k=0;k<NATOMS/1024;k++) acc[k*1024 + t] = 0.f;   // 24 stores
  __syncthreads();
  const float p = pref[0], fc = fac[0];
  const int base = b*EPB;
  #pragma unroll
  for (int k=0;k<EPB/1024;k++){    // 3 edges/thread, coalesced
    int e = base + k*1024 + t;
    int i0 = ai[e];
    int i1 = ai[NEe + e];
    float d = dist[e];
    int s0 = sp[i0], s1 = sp[i1];
    float4v n1v = *(const float4v*)(nd4 + (size_t)i1*4);
    float4v n0v = *(const float4v*)(nd4 + (size_t)i0*4);
    float x = (CUTOFF_ - d) * (1.0f/CUTOFF_);
    x = fminf(fmaxf(x, 0.f), 1.f);
    float sc = x*x*x*(x*(6.f*x - 15.f) + 10.f);
    float w = p*p * expf(-fc*fc*d) * sc;
    float a1 = (s0 < 2) ? ((s0 == 0) ? n1v[0] : n1v[1]) : ((s0 == 2) ? n1v[2] : n1v[3]);
    float a0 = (s1 < 2) ? ((s1 == 0) ? n0v[0] : n0v[1]) : ((s1 == 2) ? n0v[2] : n0v[3]);
    atomicAdd(&acc[i0], w * a1);
    atomicAdd(&acc[i1], w * a0);
  }
  __syncthreads();
  float* dst = part + (size_t)b*NATOMS;
  for (int k=t; k<NATOMS/4; k+=1024){            // 6 x float4 stores, coalesced
    *(float4v*)(dst + k*4) = *(const float4v*)(&acc[k*4]);
  }
}

// ---------- per-molecule: 256-partial reduce + charge redistribution (R8-verified) ----------
__global__ __launch_bounds__(128) void k_final(const float* __restrict__ pre,
    const float* __restrict__ part, const int* __restrict__ sp,
    const float* __restrict__ tc, float* __restrict__ out){
  __shared__ float red[128];
  int mol = blockIdx.x, t = threadIdx.x;
  float pch = 0.f; int s = 0;
  if (t < NAm){
    int a = mol*NAm + t;
    s = sp[a];
    float m = 0.f;
    #pragma unroll 8
    for (int b=0; b<PBLK; b++) m += part[(size_t)b*NATOMS + a];
    pch = pre[a] + m;
  }
  red[t] = (t < NAm) ? pch : 0.f;
  __syncthreads();
  for (int o=64; o>0; o>>=1){
    if (t < o) red[t] += red[t + o];
    __syncthreads();
  }
  float sum = red[0];
  if (t < NAm){
    out[mol*NAm + t] = (float)s;                       // species as float
    out[NATOMS + mol*NAm + t] = pch + (tc[mol] - sum) * (1.0f/96.0f);  // charges
    out[2*NATOMS + mol*NAm + t] = pch;                 // precharges
  }
}

extern "C" void kernel_launch(void* const* d_in, const int* in_sizes, int n_in,
                              void* d_out, int out_size, void* d_ws, size_t ws_size,
                              hipStream_t stream) {
  const int*   species = (const int*)  d_in[0];
  const float* X       = (const float*)d_in[1];
  const int*   ai      = (const int*)  d_in[2];
  const float* dist    = (const float*)d_in[3];
  const float* tc      = (const float*)d_in[4];
  const float* W1      = (const float*)d_in[5];
  const float* W2      = (const float*)d_in[6];
  const float* Wn      = (const float*)d_in[7];
  const float* Wf      = (const float*)d_in[8];
  const float* pref    = (const float*)d_in[9];
  const float* fac     = (const float*)d_in[10];
  float* out = (float*)d_out;

  char* w = (char*)d_ws;
  auto alloc = [&](size_t bytes)->char*{
    char* p = w; w += (bytes + 255) & ~(size_t)255; return p;
  };
  int*   Pcnt  = (int*)  alloc((size_t)HBLK*NSm*4);
  int*   sps   = (int*)  alloc(64);
  int*   order = (int*)  alloc((size_t)NATOMS*4);
  float* nd4   = (float*)alloc((size_t)NATOMS*4*4);
  float* pre   = (float*)alloc((size_t)NATOMS*4);
  float* part  = (float*)alloc((size_t)PBLK*NATOMS*4);   // 25.2 MB
  short* W1t   = (short*)alloc((size_t)W1N*2);
  short* W2t   = (short*)alloc((size_t)W2N*2);
  short* Wnt   = (short*)alloc((size_t)WNN*2);

  k_prep<<<WBLK + HBLK, 256, 0, stream>>>(W1, W2, Wn, species, W1t, W2t, Wnt, Pcnt);
  k_order<<<HBLK, 256, 0, stream>>>(species, Pcnt, sps, order);
  dim3 g(NATOMS/64, NSm);
  k_mlp<<<g, 512, 0, stream>>>(X, order, sps, W1t, W2t, Wnt, Wf, pre, nd4);
  k_eacc<<<PBLK, 1024, 0, stream>>>(ai, dist, pref, fac, species, nd4, part);
  k_final<<<NBm, 128, 0, stream>>>(pre, part, species, tc, out);
}

// Round 19
// 169.369 us; speedup vs baseline: 1.1376x; 1.0945x over previous
//
#include <hip/hip_runtime.h>
#include <cstdint>
#include <cstddef>

#define NBm 256
#define NAm 96
#define NDm 384
#define NHm 192
#define NFm 96
#define NSm 4
#define NATOMS (NBm*NAm)      /* 24576 */
#define NEe (NATOMS*32)       /* 786432 */
#define CUTOFF_ 5.2f
#define PBLK 256              /* edge-accum blocks = partial copies */
#define EPB (NEe/PBLK)        /* 3072 edges per block */
#define HBLK 96               /* NATOMS/256 hist blocks */

typedef __attribute__((ext_vector_type(8))) short short8;
typedef __attribute__((ext_vector_type(4))) float float4v;

__device__ __forceinline__ short f2bf(float f){
  union { float f; unsigned u; } v; v.f = f;
  unsigned r = v.u + 0x7FFFu + ((v.u >> 16) & 1u);
  return (short)(r >> 16);
}

// jax.nn.gelu default: tanh approximation
__device__ __forceinline__ float gelu_t(float x){
  float u = 0.7978845608028654f * (x + 0.044715f * x*x*x);
  float e = __expf(-2.0f * fabsf(u));
  float t = (1.0f - e) / (1.0f + e);
  t = (u >= 0.f) ? t : -t;
  return 0.5f * x * (1.0f + t);
}

// ---------- K1: weight prep + per-block species histogram (R14-verified) ----------
#define W1N (NSm*NDm*NHm)   /* 294912 */
#define W2N (NSm*NHm*NFm)   /* 73728 */
#define WNN (NSm*NFm*NFm)   /* 36864 */
#define WTOT (W1N+W2N+WNN)  /* 405504 */
#define WBLK (WTOT/256)     /* 1584 */
// grid = WBLK + HBLK = 1680
__global__ __launch_bounds__(256) void k_prep(
    const float* __restrict__ W1, const float* __restrict__ W2,
    const float* __restrict__ Wn, const int* __restrict__ sp,
    short* __restrict__ W1t, short* __restrict__ W2t, short* __restrict__ Wnt,
    int* __restrict__ Pcnt){
  int b = blockIdx.x;
  if (b < WBLK){
    int idx = b*256 + threadIdx.x;
    if (idx < W1N){
      int s = idx / (NDm*NHm); int rem = idx - s*NDm*NHm;
      int k = rem / NHm, c = rem - k*NHm;
      W1t[(s*NHm + c)*NDm + k] = f2bf(W1[idx]);
    } else if (idx < W1N + W2N){
      int j = idx - W1N;
      int s = j / (NHm*NFm); int rem = j - s*NHm*NFm;
      int k = rem / NFm, c = rem - k*NFm;
      W2t[(s*NFm + c)*NHm + k] = f2bf(W2[j]);
    } else {
      int j = idx - W1N - W2N;
      int s = j / (NFm*NFm); int rem = j - s*NFm*NFm;
      int k = rem / NFm, c = rem - k*NFm;
      Wnt[(s*NFm + c)*NFm + k] = f2bf(Wn[j]);
    }
  } else {
    // per-block species histogram; LDS atomics only, no pre-zero needed
    __shared__ int h[NSm];
    int t = threadIdx.x;
    if (t < NSm) h[t] = 0;
    __syncthreads();
    int i = (b - WBLK)*256 + t;
    atomicAdd(&h[sp[i]], 1);
    __syncthreads();
    if (t < NSm) Pcnt[(b - WBLK)*NSm + t] = h[t];
  }
}

// ---------- K2: redundant-scan ordering (R14-verified) ----------
__global__ __launch_bounds__(256) void k_order(const int* __restrict__ sp,
    const int* __restrict__ Pcnt, int* __restrict__ sps, int* __restrict__ order){
  __shared__ int P[HBLK][NSm];
  __shared__ int stot[NSm], spre[NSm], sscan[NSm+1];
  __shared__ int base[NSm], h[NSm];
  int t = threadIdx.x, b = blockIdx.x;
  if (t < HBLK){
    #pragma unroll
    for (int j=0;j<NSm;j++) P[t][j] = Pcnt[t*NSm + j];
  }
  if (t < NSm) h[t] = 0;
  __syncthreads();
  if (t < NSm){
    int tot = 0, pr = 0;
    for (int bb=0; bb<HBLK; bb++){
      if (bb == b) pr = tot;
      tot += P[bb][t];
    }
    stot[t] = tot; spre[t] = pr;
  }
  __syncthreads();
  if (t == 0){
    int r = 0;
    #pragma unroll
    for (int s2=0;s2<NSm;s2++){ sscan[s2] = r; r += stot[s2]; }
    sscan[NSm] = r;
    if (b == 0){
      #pragma unroll
      for (int s2=0;s2<=NSm;s2++) sps[s2] = sscan[s2];
    }
  }
  __syncthreads();
  if (t < NSm) base[t] = sscan[t] + spre[t];
  __syncthreads();
  int i = b*256 + t;
  int s = sp[i];
  int lr = atomicAdd(&h[s], 1);
  order[base[s] + lr] = i;
}

// ---------- fused MLP: R14 staged structure + register-prefetch pipelining ----------
// R15 (de-stage) and R17 (wave-split) both regressed; R14's 256-thread staged
// dataflow is the verified best. ONLY change here (T14 async-STAGE split):
// stage chunk k+1 is loaded into wreg[9] DURING chunk k's MFMA phase, so the
// L2 load latency overlaps compute instead of sitting between barriers.
// W1 chunk0 loads at kernel entry (overlap afs preload); W2 prefetched during
// GEMM1 chunk3; Wn during GEMM2. Values bit-identical to R14.
__global__ __launch_bounds__(256) void k_mlp(
    const float* __restrict__ X, const int* __restrict__ order,
    const int* __restrict__ sps,
    const short* __restrict__ W1t, const short* __restrict__ W2t,
    const short* __restrict__ Wnt, const float* __restrict__ Wf,
    float* __restrict__ pre, float* __restrict__ nd4){
  const int s = blockIdx.y;
  const int s0 = sps[s];
  const int cnt = sps[s+1] - s0;
  const int row0 = blockIdx.x * 64;
  if (row0 >= cnt) return;

  __shared__ short Hs[64][200];     // 25.6 KB
  __shared__ short Is[64][104];     // 13.3 KB
  __shared__ short Ws[19968];       // 39.9 KB staging buffer (aliased as NL below)
  __shared__ int aids[64];

  const int tid = threadIdx.x;
  const short* W1s = W1t + (size_t)s*NHm*NDm;
  const short* W2s = W2t + (size_t)s*NFm*NHm;
  const short* Wns = Wnt + (size_t)s*NFm*NFm;

  // prefetch W1 chunk 0 into registers (in flight during aids/afs preload)
  short8 wreg[9];
  #pragma unroll
  for (int i=0;i<9;i++){
    int e = tid + i*256, c = e/12, u = e - c*12;
    wreg[i] = *(const short8*)(W1s + c*NDm + u*8);
  }

  if (tid < 64){
    int r = row0 + tid;
    aids[tid] = order[s0 + ((r < cnt) ? r : 0)];
  }
  __syncthreads();

  const int wave = tid >> 6, lane = tid & 63;
  const int lrow = lane & 15, quad = lane >> 4;
  const int arow = wave*16 + lrow;
  const float* xrow = X + (size_t)aids[arow]*NDm + quad*8;

  // preload & convert all A fragments (GEMM1) up front
  short8 afs[12];
  #pragma unroll
  for (int kb=0; kb<12; kb++){
    const float* p = xrow + kb*32;
    #pragma unroll
    for (int j=0;j<8;j++) afs[kb][j] = f2bf(p[j]);
  }

  // ---- GEMM1: [64,384]@[384,192]; 4 chunks of K=96, reg-prefetch pipelined
  float4v acc[12];
  #pragma unroll
  for (int i=0;i<12;i++){ acc[i][0]=0.f; acc[i][1]=0.f; acc[i][2]=0.f; acc[i][3]=0.f; }
  for (int kc=0; kc<4; kc++){
    __syncthreads();                       // previous Ws reads complete
    #pragma unroll
    for (int i=0;i<9;i++){
      int e = tid + i*256, c = e/12, u = e - c*12;
      *(short8*)(&Ws[c*104 + u*8]) = wreg[i];
    }
    __syncthreads();                       // Ws ready
    if (kc < 3){
      #pragma unroll
      for (int i=0;i<9;i++){
        int e = tid + i*256, c = e/12, u = e - c*12;
        wreg[i] = *(const short8*)(W1s + c*NDm + (kc+1)*96 + u*8);
      }
    } else {
      // prefetch W2 during last GEMM1 chunk (96 cols x 24 units, 9/thread)
      #pragma unroll
      for (int i=0;i<9;i++){
        int e = tid + i*256, c = e/24, u = e - c*24;
        wreg[i] = *(const short8*)(W2s + c*NHm + u*8);
      }
    }
    #pragma unroll
    for (int kb3=0; kb3<3; kb3++){
      short8 af = afs[kc*3 + kb3];
      #pragma unroll
      for (int ct=0; ct<12; ct++){
        short8 bfb = *(const short8*)(&Ws[(ct*16 + lrow)*104 + kb3*32 + quad*8]);
        acc[ct] = __builtin_amdgcn_mfma_f32_16x16x32_bf16(af, bfb, acc[ct], 0,0,0);
      }
    }
  }
  // gelu -> Hs (wave-private rows, no barrier)
  #pragma unroll
  for (int ct=0; ct<12; ct++){
    #pragma unroll
    for (int r=0;r<4;r++){
      Hs[wave*16 + quad*4 + r][ct*16 + lrow] = f2bf(gelu_t(acc[ct][r]));
    }
  }

  // ---- GEMM2: [64,192]@[192,96]; W2 already in wreg
  float4v acc2[6];
  #pragma unroll
  for (int i=0;i<6;i++){ acc2[i][0]=0.f; acc2[i][1]=0.f; acc2[i][2]=0.f; acc2[i][3]=0.f; }
  __syncthreads();                         // last GEMM1 Ws reads complete
  #pragma unroll
  for (int i=0;i<9;i++){
    int e = tid + i*256, c = e/24, u = e - c*24;
    *(short8*)(&Ws[c*200 + u*8]) = wreg[i];
  }
  __syncthreads();
  // prefetch Wn during GEMM2 (96 cols x 12 units = 1152; <=5/thread guarded)
  #pragma unroll
  for (int i=0;i<5;i++){
    int e = tid + i*256;
    if (e < 96*12){
      int c = e/12, u = e - c*12;
      wreg[i] = *(const short8*)(Wns + c*NFm + u*8);
    }
  }
  for (int kb=0; kb<6; kb++){
    short8 af2 = *(const short8*)(&Hs[wave*16 + lrow][kb*32 + quad*8]);
    #pragma unroll
    for (int ct=0; ct<6; ct++){
      short8 bfb = *(const short8*)(&Ws[(ct*16 + lrow)*200 + kb*32 + quad*8]);
      acc2[ct] = __builtin_amdgcn_mfma_f32_16x16x32_bf16(af2, bfb, acc2[ct], 0,0,0);
    }
  }
  // internal -> Is (wave-private)
  #pragma unroll
  for (int ct=0; ct<6; ct++){
    #pragma unroll
    for (int r=0;r<4;r++){
      Is[wave*16 + quad*4 + r][ct*16 + lrow] = f2bf(acc2[ct][r]);
    }
  }

  // ---- epilogue A (verified since R0): pre = dot(internal_row, Wf[s][0:96])
  {
    float pr[4] = {0.f,0.f,0.f,0.f};
    #pragma unroll
    for (int ct=0; ct<6; ct++){
      float wv = Wf[s*2*NFm + ct*16 + lrow];
      #pragma unroll
      for (int r=0;r<4;r++) pr[r] += acc2[ct][r] * wv;
    }
    #pragma unroll
    for (int m=1; m<16; m<<=1){
      #pragma unroll
      for (int r=0;r<4;r++) pr[r] += __shfl_xor(pr[r], m, 64);
    }
    if (lrow == 0){
      #pragma unroll
      for (int r=0;r<4;r++){
        int row = wave*16 + quad*4 + r;
        if (row0 + row < cnt) pre[aids[row]] = pr[r];
      }
    }
  }

  // ---- GEMM3: [64,96]@[96,96]; Wn already in wreg
  float4v acc3[6];
  #pragma unroll
  for (int i=0;i<6;i++){ acc3[i][0]=0.f; acc3[i][1]=0.f; acc3[i][2]=0.f; acc3[i][3]=0.f; }
  __syncthreads();                         // GEMM2 Ws reads complete
  #pragma unroll
  for (int i=0;i<5;i++){
    int e = tid + i*256;
    if (e < 96*12){
      int c = e/12, u = e - c*12;
      *(short8*)(&Ws[c*104 + u*8]) = wreg[i];
    }
  }
  __syncthreads();
  for (int kb=0; kb<3; kb++){
    short8 af3 = *(const short8*)(&Is[wave*16 + lrow][kb*32 + quad*8]);
    #pragma unroll
    for (int ct=0; ct<6; ct++){
      short8 bfb = *(const short8*)(&Ws[(ct*16 + lrow)*104 + kb*32 + quad*8]);
      acc3[ct] = __builtin_amdgcn_mfma_f32_16x16x32_bf16(af3, bfb, acc3[ct], 0,0,0);
    }
  }

  // ---- epilogue B (LDS-staged, R12-verified): nd4[a][t2] = dot(nbr_row, Wf[t2][F:2F])
  {
    float* NL = (float*)Ws;            // Ws dead after GEMM3 reads (barrier below)
    __syncthreads();                   // all waves done reading Ws
    #pragma unroll
    for (int ct=0; ct<6; ct++){
      #pragma unroll
      for (int r=0;r<4;r++){
        NL[(wave*16 + quad*4 + r)*97 + ct*16 + lrow] = acc3[ct][r];
      }
    }
    __syncthreads();
    int row = tid >> 2, t2 = tid & 3;
    if (row0 + row < cnt){
      const float* wfp = Wf + t2*2*NFm + NFm;
      const float* nlr = NL + row*97;
      float a4 = 0.f;
      #pragma unroll 8
      for (int j=0;j<NFm;j++) a4 += nlr[j] * wfp[j];
      nd4[(size_t)aids[row]*4 + t2] = a4;
    }
  }
}

// ---------- K-eacc: edge accumulate via full-mrg LDS privatization (R8-verified) ----------
__global__ __launch_bounds__(1024) void k_eacc(const int* __restrict__ ai,
    const float* __restrict__ dist, const float* __restrict__ pref,
    const float* __restrict__ fac, const int* __restrict__ sp,
    const float* __restrict__ nd4, float* __restrict__ part){
  __shared__ float acc[NATOMS];    // 96 KB
  const int t = threadIdx.x, b = blockIdx.x;
  #pragma unroll
  for (int k=0;k<NATOMS/1024;k++) acc[k*1024 + t] = 0.f;   // 24 stores
  __syncthreads();
  const float p = pref[0], fc = fac[0];
  const int base = b*EPB;
  #pragma unroll
  for (int k=0;k<EPB/1024;k++){    // 3 edges/thread, coalesced
    int e = base + k*1024 + t;
    int i0 = ai[e];
    int i1 = ai[NEe + e];
    float d = dist[e];
    int s0 = sp[i0], s1 = sp[i1];
    float4v n1v = *(const float4v*)(nd4 + (size_t)i1*4);
    float4v n0v = *(const float4v*)(nd4 + (size_t)i0*4);
    float x = (CUTOFF_ - d) * (1.0f/CUTOFF_);
    x = fminf(fmaxf(x, 0.f), 1.f);
    float sc = x*x*x*(x*(6.f*x - 15.f) + 10.f);
    float w = p*p * expf(-fc*fc*d) * sc;
    float a1 = (s0 < 2) ? ((s0 == 0) ? n1v[0] : n1v[1]) : ((s0 == 2) ? n1v[2] : n1v[3]);
    float a0 = (s1 < 2) ? ((s1 == 0) ? n0v[0] : n0v[1]) : ((s1 == 2) ? n0v[2] : n0v[3]);
    atomicAdd(&acc[i0], w * a1);
    atomicAdd(&acc[i1], w * a0);
  }
  __syncthreads();
  float* dst = part + (size_t)b*NATOMS;
  for (int k=t; k<NATOMS/4; k+=1024){            // 6 x float4 stores, coalesced
    *(float4v*)(dst + k*4) = *(const float4v*)(&acc[k*4]);
  }
}

// ---------- per-molecule: 256-partial reduce + charge redistribution (R8-verified) ----------
__global__ __launch_bounds__(128) void k_final(const float* __restrict__ pre,
    const float* __restrict__ part, const int* __restrict__ sp,
    const float* __restrict__ tc, float* __restrict__ out){
  __shared__ float red[128];
  int mol = blockIdx.x, t = threadIdx.x;
  float pch = 0.f; int s = 0;
  if (t < NAm){
    int a = mol*NAm + t;
    s = sp[a];
    float m = 0.f;
    #pragma unroll 8
    for (int b=0; b<PBLK; b++) m += part[(size_t)b*NATOMS + a];
    pch = pre[a] + m;
  }
  red[t] = (t < NAm) ? pch : 0.f;
  __syncthreads();
  for (int o=64; o>0; o>>=1){
    if (t < o) red[t] += red[t + o];
    __syncthreads();
  }
  float sum = red[0];
  if (t < NAm){
    out[mol*NAm + t] = (float)s;                       // species as float
    out[NATOMS + mol*NAm + t] = pch + (tc[mol] - sum) * (1.0f/96.0f);  // charges
    out[2*NATOMS + mol*NAm + t] = pch;                 // precharges
  }
}

extern "C" void kernel_launch(void* const* d_in, const int* in_sizes, int n_in,
                              void* d_out, int out_size, void* d_ws, size_t ws_size,
                              hipStream_t stream) {
  const int*   species = (const int*)  d_in[0];
  const float* X       = (const float*)d_in[1];
  const int*   ai      = (const int*)  d_in[2];
  const float* dist    = (const float*)d_in[3];
  const float* tc      = (const float*)d_in[4];
  const float* W1      = (const float*)d_in[5];
  const float* W2      = (const float*)d_in[6];
  const float* Wn      = (const float*)d_in[7];
  const float* Wf      = (const float*)d_in[8];
  const float* pref    = (const float*)d_in[9];
  const float* fac     = (const float*)d_in[10];
  float* out = (float*)d_out;

  char* w = (char*)d_ws;
  auto alloc = [&](size_t bytes)->char*{
    char* p = w; w += (bytes + 255) & ~(size_t)255; return p;
  };
  int*   Pcnt  = (int*)  alloc((size_t)HBLK*NSm*4);
  int*   sps   = (int*)  alloc(64);
  int*   order = (int*)  alloc((size_t)NATOMS*4);
  float* nd4   = (float*)alloc((size_t)NATOMS*4*4);
  float* pre   = (float*)alloc((size_t)NATOMS*4);
  float* part  = (float*)alloc((size_t)PBLK*NATOMS*4);   // 25.2 MB
  short* W1t   = (short*)alloc((size_t)W1N*2);
  short* W2t   = (short*)alloc((size_t)W2N*2);
  short* Wnt   = (short*)alloc((size_t)WNN*2);

  k_prep<<<WBLK + HBLK, 256, 0, stream>>>(W1, W2, Wn, species, W1t, W2t, Wnt, Pcnt);
  k_order<<<HBLK, 256, 0, stream>>>(species, Pcnt, sps, order);
  dim3 g(NATOMS/64, NSm);
  k_mlp<<<g, 256, 0, stream>>>(X, order, sps, W1t, W2t, Wnt, Wf, pre, nd4);
  k_eacc<<<PBLK, 1024, 0, stream>>>(ai, dist, pref, fac, species, nd4, part);
  k_final<<<NBm, 128, 0, stream>>>(pre, part, species, tc, out);
}